// Round 21
// baseline (50.072 us; speedup 1.0000x reference)
//
#include <hip/hip_runtime.h>
#include <hip/hip_bf16.h>

// Problem constants (hardcoded in the reference)
#define B_SZ 512
#define D_SZ 1024
#define NK 160
#define NCOL 480          // NK*3
#define OUTW 1184         // D + NK
#define LOG2E 1.44269504088896340736f
#define PLANE 245760      // 480*512 floats per K-half partial plane

typedef __attribute__((ext_vector_type(8))) short bf16x8;
typedef __attribute__((ext_vector_type(4))) float f32x4;

__device__ __forceinline__ unsigned int f32_bf16_rne(float f) {
    unsigned int u = __float_as_uint(f);
    u += 0x7fffu + ((u >> 16) & 1u);   // round-to-nearest-even at bf16 boundary
    return u >> 16;
}
__device__ __forceinline__ unsigned int pk2(float x, float y) {
    return f32_bf16_rne(x) | (f32_bf16_rne(y) << 16);
}

// ---------------- Dispatch 1: single-shot MFMA GEMM (r14-identical) +
// feat zeroing by the first 320 blocks (replaces a memset node).
__global__ __launch_bounds__(256, 2) void mbd_gemm_kernel(
    const float* __restrict__ A,      // [512][1024]
    const float* __restrict__ W,      // [1024][480]
    const float* __restrict__ bias,   // [480]
    float* __restrict__ act2,         // ws: [2][480][512] f32
    float* __restrict__ feat)         // ws: [512][160] f32 (zeroed here)
{
    __shared__ char lds[65536];       // A [32 rows][1024B] @0 ; W [32 cols][1024B] @32768
    const int bid = blockIdx.x;       // 0..479
    const int t = threadIdx.x;

    if (bid < 320) feat[bid * 256 + t] = 0.f;   // 320*256 = 81920 = 512*160

    const int xcd = bid & 7, loc = bid >> 3;    // loc 0..59
    const int bm = xcd * 2 + (loc & 1);         // 0..15 (XCD-local A rows)
    const int ksp = (loc >> 1) & 1;             // K-half
    const int bn = loc >> 2;                    // 0..14
    const int i0 = bm * 32, c0 = bn * 32, kb0 = ksp * 512;
    const int w = __builtin_amdgcn_readfirstlane(t >> 6);  // 0..3 uniform
    const int l = t & 63, lhi = l >> 4, llo = l & 15;

    const int arow = t >> 3, aseg = t & 7;
    const int aswz = (arow & 7) << 4;
    const float* __restrict__ aptr = A + (size_t)(i0 + arow) * D_SZ + kb0 + aseg * 4;
    const int kp8 = t >> 3, cq = t & 7;
    const float* __restrict__ wbase = W + (size_t)(kb0 + 2 * kp8) * NCOL + c0 + 4 * cq;

    float4 ra[16], rw0[8], rw1[8];
#pragma unroll
    for (int q = 0; q < 16; ++q)
        ra[q] = *reinterpret_cast<const float4*>(aptr + q * 32);
#pragma unroll
    for (int m = 0; m < 8; ++m) {
        rw0[m] = *reinterpret_cast<const float4*>(wbase + (size_t)(64 * m) * NCOL);
        rw1[m] = *reinterpret_cast<const float4*>(wbase + (size_t)(64 * m + 1) * NCOL);
    }

    {
        char* arp = lds + arow * 1024;
#pragma unroll
        for (int q = 0; q < 16; ++q) {
            uint2 p;
            p.x = pk2(ra[q].x, ra[q].y);
            p.y = pk2(ra[q].z, ra[q].w);
            *reinterpret_cast<uint2*>(arp + ((aseg * 8 + 64 * q) ^ aswz)) = p;
        }
#pragma unroll
        for (int m = 0; m < 8; ++m) {
            const int p = kp8 + 32 * m;
#pragma unroll
            for (int j = 0; j < 4; ++j) {
                const int col = 4 * cq + j;
                const float v0 = (&rw0[m].x)[j];
                const float v1 = (&rw1[m].x)[j];
                *reinterpret_cast<unsigned int*>(
                    lds + 32768 + col * 1024 + ((4 * p) ^ ((col & 7) << 4))) = pk2(v0, v1);
            }
        }
    }
    __syncthreads();                   // the ONLY barrier

    f32x4 acc = {0.f, 0.f, 0.f, 0.f};
    const int r0 = (w & 1) * 16, cc = (w >> 1) * 16;
    const int lswz = (llo & 7) << 4;
#pragma unroll
    for (int m = 0; m < 16; ++m) {
        const int koff = (lhi * 16 + m * 64) ^ lswz;
        const bf16x8 af = *reinterpret_cast<const bf16x8*>(lds + (r0 + llo) * 1024 + koff);
        const bf16x8 bf = *reinterpret_cast<const bf16x8*>(lds + 32768 + (cc + llo) * 1024 + koff);
        acc = __builtin_amdgcn_mfma_f32_16x16x32_bf16(af, bf, acc, 0, 0, 0);
    }

    const int col = c0 + cc + llo;
    const float bs = ksp ? 0.f : bias[col];
    float4 o;
    o.x = (acc[0] + bs) * LOG2E;
    o.y = (acc[1] + bs) * LOG2E;
    o.z = (acc[2] + bs) * LOG2E;
    o.w = (acc[3] + bs) * LOG2E;
    *reinterpret_cast<float4*>(
        &act2[(size_t)ksp * PLANE + (size_t)col * B_SZ + i0 + r0 + lhi * 4]) = o;
}

// ---------------- Dispatch 2: SYMMETRIC pairwise. Block = (k, chunk-pair
// ci<=cj over 8 chunks of 64 rows); 64 thr. Each 64x64 tile computed once:
// lane (a=l&7, b=l>>3) does an 8x8 sub-block, accumulating row-sums and
// col-sums; shfl reduces; atomicAdd into feat[row][k]. Diagonal blocks
// (ci==cj) contribute row-sums only (full tile computed, both triangles).
// exp count: 0.5625x of the dense version -> attacks the trans-pipe bound.
__global__ __launch_bounds__(64) void mbd_pairsym_kernel(
    const float* __restrict__ act2,    // [2][480][512]
    float* __restrict__ feat)          // [512][160], pre-zeroed
{
    __shared__ float4 as4[128];        // rows: [0..63]=chunk ci, [64..127]=chunk cj
    const int bid = blockIdx.x;        // 0..5759
    const int lin = (bid & 7) * 720 + (bid >> 3);   // XCD-bijective (5760 = 8x720)
    const int k = lin / 36;            // 0..159
    int p = lin % 36;                  // chunk-pair index
    int ci = 0;
    while (p >= 8 - ci) { p -= 8 - ci; ++ci; }
    const int cj = ci + p;             // ci <= cj
    const int t = threadIdx.x;         // 0..63

    const float* __restrict__ p0 = act2 + (size_t)(3 * k + 0) * B_SZ;
    const float* __restrict__ p1 = act2 + (size_t)(3 * k + 1) * B_SZ;
    const float* __restrict__ p2 = act2 + (size_t)(3 * k + 2) * B_SZ;
    {
        const int ra = ci * 64 + t;
        as4[t] = make_float4(p0[ra] + p0[ra + PLANE],
                             p1[ra] + p1[ra + PLANE],
                             p2[ra] + p2[ra + PLANE], 0.f);
        const int rb = cj * 64 + t;
        as4[64 + t] = make_float4(p0[rb] + p0[rb + PLANE],
                                  p1[rb] + p1[rb + PLANE],
                                  p2[rb] + p2[rb + PLANE], 0.f);
    }
    __syncthreads();

    const int a = t & 7;               // row group (8 rows of chunk ci)
    const int b = t >> 3;              // col group (8 cols of chunk cj)
    float rx[8], ry[8], rz[8], ar[8], ac[8];
#pragma unroll
    for (int i = 0; i < 8; ++i) {
        const float4 v = as4[a * 8 + i];
        rx[i] = v.x; ry[i] = v.y; rz[i] = v.z;
        ar[i] = 0.f; ac[i] = 0.f;
    }

#pragma unroll
    for (int c = 0; c < 8; ++c) {
        const float4 cv = as4[64 + b * 8 + c];
#pragma unroll
        for (int r = 0; r < 8; ++r) {
            const float e = __builtin_amdgcn_exp2f(
                -(fabsf(rx[r] - cv.x) + fabsf(ry[r] - cv.y) + fabsf(rz[r] - cv.z)));
            ar[r] += e;
            ac[c] += e;
        }
    }
    // row-sums: reduce over b (lane bits 3..5); col-sums: reduce over a (bits 0..2)
#pragma unroll
    for (int m = 8; m <= 32; m <<= 1)
#pragma unroll
        for (int i = 0; i < 8; ++i) ar[i] += __shfl_xor(ar[i], m);
#pragma unroll
    for (int m = 1; m <= 4; m <<= 1)
#pragma unroll
        for (int i = 0; i < 8; ++i) ac[i] += __shfl_xor(ac[i], m);

    if (b == 0) {                      // 8 lanes (a=0..7), each adds 8 row totals
#pragma unroll
        for (int r = 0; r < 8; ++r)
            atomicAdd(&feat[(size_t)(ci * 64 + a * 8 + r) * NK + k], ar[r]);
    }
    if (ci != cj && a == 0) {          // transpose side: col totals -> cj rows
#pragma unroll
        for (int c = 0; c < 8; ++c)
            atomicAdd(&feat[(size_t)(cj * 64 + b * 8 + c) * NK + k], ac[c]);
    }
}

// ---------------- Dispatch 3: output assembly. Block = one row: copy the
// 1024 inputs + gather 160 features (feat[i][k] row-major -> coalesced).
__global__ __launch_bounds__(64) void mbd_out_kernel(
    const float* __restrict__ A,       // [512][1024]
    const float* __restrict__ feat,    // [512][160]
    float* __restrict__ out)           // [512][1184]
{
    const int i = blockIdx.x;          // row 0..511
    const int t = threadIdx.x;         // 0..63
#pragma unroll
    for (int s = 0; s < 4; ++s) {
        const int c4 = (t + s * 64) * 4;
        const float4 v = *reinterpret_cast<const float4*>(&A[i * D_SZ + c4]);
        *reinterpret_cast<float4*>(&out[i * OUTW + c4]) = v;
    }
#pragma unroll
    for (int s = 0; s < 3; ++s) {
        const int idx = t + s * 64;
        if (idx < NK)
            out[i * OUTW + D_SZ + idx] = feat[(size_t)i * NK + idx];
    }
}

extern "C" void kernel_launch(void* const* d_in, const int* in_sizes, int n_in,
                              void* d_out, int out_size, void* d_ws, size_t ws_size,
                              hipStream_t stream)
{
    const float* inputs = (const float*)d_in[0];   // [512,1024] f32
    const float* W      = (const float*)d_in[1];   // [1024,480] f32
    const float* bias   = (const float*)d_in[2];   // [480] f32
    float* out = (float*)d_out;                    // [512,1184] f32

    char* ws = (char*)d_ws;
    float* act2 = (float*)ws;                      // [2][480][512] = 1,966,080 B
    float* feat = (float*)(ws + 1966080);          // [512][160]    =   327,680 B

    mbd_gemm_kernel<<<480, 256, 0, stream>>>(inputs, W, bias, act2, feat);
    mbd_pairsym_kernel<<<160 * 36, 64, 0, stream>>>(act2, feat);
    mbd_out_kernel<<<B_SZ, 64, 0, stream>>>(inputs, feat, out);
}

// Round 22
// 23.276 us; speedup vs baseline: 2.1513x; 2.1513x over previous
//
#include <hip/hip_runtime.h>
#include <hip/hip_bf16.h>

// Problem constants (hardcoded in the reference)
#define B_SZ 512
#define D_SZ 1024
#define NK 160
#define NCOL 480          // NK*3
#define OUTW 1184         // D + NK
#define LOG2E 1.44269504088896340736f
#define PLANE 245760      // 480*512 floats per K-half partial plane

typedef __attribute__((ext_vector_type(8))) short bf16x8;
typedef __attribute__((ext_vector_type(4))) float f32x4;

__device__ __forceinline__ unsigned int f32_bf16_rne(float f) {
    unsigned int u = __float_as_uint(f);
    u += 0x7fffu + ((u >> 16) & 1u);   // round-to-nearest-even at bf16 boundary
    return u >> 16;
}
__device__ __forceinline__ unsigned int pk2(float x, float y) {
    return f32_bf16_rne(x) | (f32_bf16_rne(y) << 16);
}

// ---------------- Dispatch 1: single-shot MFMA GEMM (byte-identical to r14/r17/r19).
__global__ __launch_bounds__(256, 2) void mbd_gemm_kernel(
    const float* __restrict__ A,      // [512][1024]
    const float* __restrict__ W,      // [1024][480]
    const float* __restrict__ bias,   // [480]
    float* __restrict__ act2)         // ws: [2][480][512] f32
{
    __shared__ char lds[65536];       // A [32 rows][1024B] @0 ; W [32 cols][1024B] @32768
    const int bid = blockIdx.x;       // 0..479
    const int xcd = bid & 7, loc = bid >> 3;    // loc 0..59
    const int bm = xcd * 2 + (loc & 1);         // 0..15 (XCD-local A rows)
    const int ksp = (loc >> 1) & 1;             // K-half
    const int bn = loc >> 2;                    // 0..14
    const int i0 = bm * 32, c0 = bn * 32, kb0 = ksp * 512;
    const int t = threadIdx.x;
    const int w = __builtin_amdgcn_readfirstlane(t >> 6);  // 0..3 uniform
    const int l = t & 63, lhi = l >> 4, llo = l & 15;

    const int arow = t >> 3, aseg = t & 7;
    const int aswz = (arow & 7) << 4;
    const float* __restrict__ aptr = A + (size_t)(i0 + arow) * D_SZ + kb0 + aseg * 4;
    const int kp8 = t >> 3, cq = t & 7;
    const float* __restrict__ wbase = W + (size_t)(kb0 + 2 * kp8) * NCOL + c0 + 4 * cq;

    float4 ra[16], rw0[8], rw1[8];
#pragma unroll
    for (int q = 0; q < 16; ++q)
        ra[q] = *reinterpret_cast<const float4*>(aptr + q * 32);
#pragma unroll
    for (int m = 0; m < 8; ++m) {
        rw0[m] = *reinterpret_cast<const float4*>(wbase + (size_t)(64 * m) * NCOL);
        rw1[m] = *reinterpret_cast<const float4*>(wbase + (size_t)(64 * m + 1) * NCOL);
    }

    {
        char* arp = lds + arow * 1024;
#pragma unroll
        for (int q = 0; q < 16; ++q) {
            uint2 p;
            p.x = pk2(ra[q].x, ra[q].y);
            p.y = pk2(ra[q].z, ra[q].w);
            *reinterpret_cast<uint2*>(arp + ((aseg * 8 + 64 * q) ^ aswz)) = p;
        }
#pragma unroll
        for (int m = 0; m < 8; ++m) {
            const int p = kp8 + 32 * m;
#pragma unroll
            for (int j = 0; j < 4; ++j) {
                const int col = 4 * cq + j;
                const float v0 = (&rw0[m].x)[j];
                const float v1 = (&rw1[m].x)[j];
                *reinterpret_cast<unsigned int*>(
                    lds + 32768 + col * 1024 + ((4 * p) ^ ((col & 7) << 4))) = pk2(v0, v1);
            }
        }
    }
    __syncthreads();                   // the ONLY barrier

    f32x4 acc = {0.f, 0.f, 0.f, 0.f};
    const int r0 = (w & 1) * 16, cc = (w >> 1) * 16;
    const int lswz = (llo & 7) << 4;
#pragma unroll
    for (int m = 0; m < 16; ++m) {
        const int koff = (lhi * 16 + m * 64) ^ lswz;
        const bf16x8 af = *reinterpret_cast<const bf16x8*>(lds + (r0 + llo) * 1024 + koff);
        const bf16x8 bf = *reinterpret_cast<const bf16x8*>(lds + 32768 + (cc + llo) * 1024 + koff);
        acc = __builtin_amdgcn_mfma_f32_16x16x32_bf16(af, bf, acc, 0, 0, 0);
    }

    const int col = c0 + cc + llo;
    const float bs = ksp ? 0.f : bias[col];
    float4 o;
    o.x = (acc[0] + bs) * LOG2E;
    o.y = (acc[1] + bs) * LOG2E;
    o.z = (acc[2] + bs) * LOG2E;
    o.w = (acc[3] + bs) * LOG2E;
    *reinterpret_cast<float4*>(
        &act2[(size_t)ksp * PLANE + (size_t)col * B_SZ + i0 + r0 + lhi * 4]) = o;
}

// ---------------- Dispatch 2: pairwise, 640 blocks x 512 thr (same 20 waves/CU
// as r17, same inner loop), but 128 rows per block: staging count per k halves
// (4 blocks/k vs 8) and each thread stages 1 LDS entry instead of 2 — attacks
// the rep-independent ~8us fixed pocket (staging latency x #blocks).
__global__ __launch_bounds__(512) void mbd_pairwise_kernel(
    const float* __restrict__ A,       // [512][1024] (for the copy)
    const float* __restrict__ act2,    // [2][480][512]
    float* __restrict__ out)           // [512][1184]
{
    __shared__ float4 as4[B_SZ];
    const int bid = blockIdx.x;        // 0..639
    const int t = threadIdx.x;         // 0..511

    if (bid < 512 && t < 256) {        // fused input copy: one row per block
        const float4 v = *reinterpret_cast<const float4*>(&A[bid * D_SZ + t * 4]);
        *reinterpret_cast<float4*>(&out[bid * OUTW + t * 4]) = v;
    }

    const int klin = (bid & 7) * 80 + (bid >> 3);   // XCD-bijective (640 = 8x80)
    const int k = klin >> 2;           // 0..159
    const int c = klin & 3;            // 0..3 (128-row chunk)

    const float* __restrict__ p0 = act2 + (size_t)(3 * k + 0) * B_SZ;
    const float* __restrict__ p1 = act2 + (size_t)(3 * k + 1) * B_SZ;
    const float* __restrict__ p2 = act2 + (size_t)(3 * k + 2) * B_SZ;
    as4[t] = make_float4(p0[t] + p0[t + PLANE],
                         p1[t] + p1[t + PLANE],
                         p2[t] + p2[t + PLANE], 0.f);
    __syncthreads();

    const int w = t >> 6, lane = t & 63;   // 8 waves
    const int rg = lane & 1;           // 0..1 row group
    const int jq = lane >> 1;          // 0..31 j-slice
    const int r0 = c * 128 + w * 16 + rg * 8;

    float ax[8], ay[8], az[8], acc[8];
#pragma unroll
    for (int i = 0; i < 8; ++i) {
        const float4 v = as4[r0 + i];
        ax[i] = v.x; ay[i] = v.y; az[i] = v.z;
        acc[i] = 0.f;
    }

#pragma unroll 4
    for (int jj = 0; jj < 16; ++jj) {
        const float4 av = as4[jq + jj * 32];
#pragma unroll
        for (int i = 0; i < 8; ++i)
            acc[i] += __builtin_amdgcn_exp2f(
                -(fabsf(ax[i] - av.x) + fabsf(ay[i] - av.y) + fabsf(az[i] - av.z)));
    }
    // reduce the 32 j-slices (lane bits 1..5)
#pragma unroll
    for (int m = 2; m <= 32; m <<= 1) {
#pragma unroll
        for (int i = 0; i < 8; ++i) acc[i] += __shfl_xor(acc[i], m);
    }
    if (lane < 2) {                    // rg == lane, jq == 0
#pragma unroll
        for (int i = 0; i < 8; ++i)
            out[(size_t)(r0 + i) * OUTW + D_SZ + k] = acc[i];
    }
}

extern "C" void kernel_launch(void* const* d_in, const int* in_sizes, int n_in,
                              void* d_out, int out_size, void* d_ws, size_t ws_size,
                              hipStream_t stream)
{
    const float* inputs = (const float*)d_in[0];   // [512,1024] f32
    const float* W      = (const float*)d_in[1];   // [1024,480] f32
    const float* bias   = (const float*)d_in[2];   // [480] f32
    float* out = (float*)d_out;                    // [512,1184] f32
    float* act2 = (float*)d_ws;                    // [2][480][512] f32 = 1,966,080 B

    mbd_gemm_kernel<<<480, 256, 0, stream>>>(inputs, W, bias, act2);
    mbd_pairwise_kernel<<<640, 512, 0, stream>>>(inputs, act2, out);
}

// Round 23
// 21.725 us; speedup vs baseline: 2.3048x; 1.0714x over previous
//
#include <hip/hip_runtime.h>
#include <hip/hip_bf16.h>

// Problem constants (hardcoded in the reference)
#define B_SZ 512
#define D_SZ 1024
#define NK 160
#define NCOL 480          // NK*3
#define OUTW 1184         // D + NK
#define LOG2E 1.44269504088896340736f
#define PLANE 245760      // 480*512 floats per K-half partial plane

typedef __attribute__((ext_vector_type(8))) short bf16x8;
typedef __attribute__((ext_vector_type(4))) float f32x4;

__device__ __forceinline__ unsigned int f32_bf16_rne(float f) {
    unsigned int u = __float_as_uint(f);
    u += 0x7fffu + ((u >> 16) & 1u);   // round-to-nearest-even at bf16 boundary
    return u >> 16;
}
__device__ __forceinline__ unsigned int pk2(float x, float y) {
    return f32_bf16_rne(x) | (f32_bf16_rne(y) << 16);
}

// ---------------- Dispatch 1: single-shot MFMA GEMM (r14-verified, session best).
// 480 blocks x 256 thr (2 blocks/CU). Block = 32(M) x 32(N) tile, K-half 512
// split across blocks. Stage ALL of A(32x512)+W(32x512) as bf16 into 64KB LDS
// in ONE load burst -> one latency exposure -> ONE barrier -> 16 MFMA/wave.
__global__ __launch_bounds__(256, 2) void mbd_gemm_kernel(
    const float* __restrict__ A,      // [512][1024]
    const float* __restrict__ W,      // [1024][480]
    const float* __restrict__ bias,   // [480]
    float* __restrict__ act2)         // ws: [2][480][512] f32
{
    __shared__ char lds[65536];       // A [32 rows][1024B] @0 ; W [32 cols][1024B] @32768
    const int bid = blockIdx.x;       // 0..479
    const int xcd = bid & 7, loc = bid >> 3;    // loc 0..59
    const int bm = xcd * 2 + (loc & 1);         // 0..15 (XCD-local A rows)
    const int ksp = (loc >> 1) & 1;             // K-half
    const int bn = loc >> 2;                    // 0..14
    const int i0 = bm * 32, c0 = bn * 32, kb0 = ksp * 512;
    const int t = threadIdx.x;
    const int w = __builtin_amdgcn_readfirstlane(t >> 6);  // 0..3 uniform
    const int l = t & 63, lhi = l >> 4, llo = l & 15;

    const int arow = t >> 3, aseg = t & 7;
    const int aswz = (arow & 7) << 4;
    const float* __restrict__ aptr = A + (size_t)(i0 + arow) * D_SZ + kb0 + aseg * 4;
    const int kp8 = t >> 3, cq = t & 7;
    const float* __restrict__ wbase = W + (size_t)(kb0 + 2 * kp8) * NCOL + c0 + 4 * cq;

    float4 ra[16], rw0[8], rw1[8];
#pragma unroll
    for (int q = 0; q < 16; ++q)
        ra[q] = *reinterpret_cast<const float4*>(aptr + q * 32);
#pragma unroll
    for (int m = 0; m < 8; ++m) {
        rw0[m] = *reinterpret_cast<const float4*>(wbase + (size_t)(64 * m) * NCOL);
        rw1[m] = *reinterpret_cast<const float4*>(wbase + (size_t)(64 * m + 1) * NCOL);
    }

    {
        char* arp = lds + arow * 1024;
#pragma unroll
        for (int q = 0; q < 16; ++q) {
            uint2 p;
            p.x = pk2(ra[q].x, ra[q].y);
            p.y = pk2(ra[q].z, ra[q].w);
            *reinterpret_cast<uint2*>(arp + ((aseg * 8 + 64 * q) ^ aswz)) = p;
        }
#pragma unroll
        for (int m = 0; m < 8; ++m) {
            const int p = kp8 + 32 * m;
#pragma unroll
            for (int j = 0; j < 4; ++j) {
                const int col = 4 * cq + j;
                const float v0 = (&rw0[m].x)[j];
                const float v1 = (&rw1[m].x)[j];
                *reinterpret_cast<unsigned int*>(
                    lds + 32768 + col * 1024 + ((4 * p) ^ ((col & 7) << 4))) = pk2(v0, v1);
            }
        }
    }
    __syncthreads();                   // the ONLY barrier

    f32x4 acc = {0.f, 0.f, 0.f, 0.f};
    const int r0 = (w & 1) * 16, cc = (w >> 1) * 16;
    const int lswz = (llo & 7) << 4;
#pragma unroll
    for (int m = 0; m < 16; ++m) {
        const int koff = (lhi * 16 + m * 64) ^ lswz;
        const bf16x8 af = *reinterpret_cast<const bf16x8*>(lds + (r0 + llo) * 1024 + koff);
        const bf16x8 bf = *reinterpret_cast<const bf16x8*>(lds + 32768 + (cc + llo) * 1024 + koff);
        acc = __builtin_amdgcn_mfma_f32_16x16x32_bf16(af, bf, acc, 0, 0, 0);
    }

    const int col = c0 + cc + llo;
    const float bs = ksp ? 0.f : bias[col];
    float4 o;   // C/D layout: col = lane&15, row = (lane>>4)*4 + reg
    o.x = (acc[0] + bs) * LOG2E;
    o.y = (acc[1] + bs) * LOG2E;
    o.z = (acc[2] + bs) * LOG2E;
    o.w = (acc[3] + bs) * LOG2E;
    *reinterpret_cast<float4*>(
        &act2[(size_t)ksp * PLANE + (size_t)col * B_SZ + i0 + r0 + lhi * 4]) = o;
}

// ---------------- Dispatch 2: pairwise at 20 waves/CU (r17-verified, session best).
// 1280 blocks x 256 thr. Block = (k, 64-row chunk c); wave w: rows
// c*64 + w*16 + rg*8 (rg=lane&1), jq=lane>>1 -> 32 j-slices of 16.
// 8 rows per ds_read_b128 broadcast. Copy fused in bid<512.
__global__ __launch_bounds__(256) void mbd_pairwise_kernel(
    const float* __restrict__ A,       // [512][1024] (for the copy)
    const float* __restrict__ act2,    // [2][480][512]
    float* __restrict__ out)           // [512][1184]
{
    __shared__ float4 as4[B_SZ];
    const int bid = blockIdx.x;        // 0..1279
    const int t = threadIdx.x;         // 0..255

    if (bid < 512) {                   // fused input copy: one row per block
        const float4 v = *reinterpret_cast<const float4*>(&A[bid * D_SZ + t * 4]);
        *reinterpret_cast<float4*>(&out[bid * OUTW + t * 4]) = v;
    }

    const int klin = (bid & 7) * 160 + (bid >> 3);   // XCD-bijective (1280 = 8x160)
    const int k = klin >> 3;           // 0..159
    const int c = klin & 7;            // 0..7 (64-row chunk)

    const float* __restrict__ p0 = act2 + (size_t)(3 * k + 0) * B_SZ;
    const float* __restrict__ p1 = act2 + (size_t)(3 * k + 1) * B_SZ;
    const float* __restrict__ p2 = act2 + (size_t)(3 * k + 2) * B_SZ;
#pragma unroll
    for (int s = 0; s < 2; ++s) {
        const int idx = t + s * 256;
        as4[idx] = make_float4(p0[idx] + p0[idx + PLANE],
                               p1[idx] + p1[idx + PLANE],
                               p2[idx] + p2[idx + PLANE], 0.f);
    }
    __syncthreads();

    const int w = t >> 6, lane = t & 63;
    const int rg = lane & 1;           // 0..1 row group
    const int jq = lane >> 1;          // 0..31 j-slice
    const int r0 = c * 64 + w * 16 + rg * 8;

    float ax[8], ay[8], az[8], acc[8];
#pragma unroll
    for (int i = 0; i < 8; ++i) {
        const float4 v = as4[r0 + i];
        ax[i] = v.x; ay[i] = v.y; az[i] = v.z;
        acc[i] = 0.f;
    }

#pragma unroll 4
    for (int jj = 0; jj < 16; ++jj) {
        const float4 av = as4[jq + jj * 32];
#pragma unroll
        for (int i = 0; i < 8; ++i)
            acc[i] += __builtin_amdgcn_exp2f(
                -(fabsf(ax[i] - av.x) + fabsf(ay[i] - av.y) + fabsf(az[i] - av.z)));
    }
    // reduce the 32 j-slices (lane bits 1..5)
#pragma unroll
    for (int m = 2; m <= 32; m <<= 1) {
#pragma unroll
        for (int i = 0; i < 8; ++i) acc[i] += __shfl_xor(acc[i], m);
    }
    if (lane < 2) {                    // rg == lane, jq == 0
#pragma unroll
        for (int i = 0; i < 8; ++i)
            out[(size_t)(r0 + i) * OUTW + D_SZ + k] = acc[i];
    }
}

extern "C" void kernel_launch(void* const* d_in, const int* in_sizes, int n_in,
                              void* d_out, int out_size, void* d_ws, size_t ws_size,
                              hipStream_t stream)
{
    const float* inputs = (const float*)d_in[0];   // [512,1024] f32
    const float* W      = (const float*)d_in[1];   // [1024,480] f32
    const float* bias   = (const float*)d_in[2];   // [480] f32
    float* out = (float*)d_out;                    // [512,1184] f32
    float* act2 = (float*)d_ws;                    // [2][480][512] f32 = 1,966,080 B

    mbd_gemm_kernel<<<480, 256, 0, stream>>>(inputs, W, bias, act2);
    mbd_pairwise_kernel<<<1280, 256, 0, stream>>>(inputs, act2, out);
}